// Round 1
// baseline (951.131 us; speedup 1.0000x reference)
//
#include <hip/hip_runtime.h>

typedef __attribute__((ext_vector_type(8))) short bf16x8;
typedef __attribute__((ext_vector_type(4))) float f32x4;
typedef __attribute__((ext_vector_type(8))) unsigned short u16x8;

__device__ inline unsigned short f2bf(float f) {
  unsigned int u = __float_as_uint(f);
  u += 0x7fffu + ((u >> 16) & 1u);
  return (unsigned short)(u >> 16);
}

__device__ inline void gload_lds16(const void* g, void* l) {
  __builtin_amdgcn_global_load_lds(
      (const __attribute__((address_space(1))) void*)g,
      (__attribute__((address_space(3))) void*)l, 16, 0, 0);
}

// ---------------- weight transpose + bf16 cast: W[K][N] -> Wt[N][K] ----------
__global__ void wtrans(const float* __restrict__ W, unsigned short* __restrict__ Wt,
                       int K, int N) {
  int idx = blockIdx.x * 256 + threadIdx.x;
  if (idx >= K * N) return;
  int k = idx / N, n = idx - k * N;
  Wt[(size_t)n * K + k] = f2bf(W[idx]);
}

// ---------------- LayerNorm (+ optional shift/window gather), f32 -> bf16 ----
// MODE 0: output token t is windowed order; gather from shifted original pos.
// MODE 1: identity order (LN2 on x1).
template <int MODE>
__global__ void ln_k(const float* __restrict__ x, const float* __restrict__ sc,
                     const float* __restrict__ bi, unsigned short* __restrict__ o) {
  int t = blockIdx.x * 4 + (threadIdx.x >> 6);
  int l = threadIdx.x & 63;
  size_t src;
  if (MODE == 0) {
    int b = t / 28800, r = t - b * 28800;
    int win = r / 144, tok = r - win * 144;
    int c1 = win / 100, rem = win - c1 * 100;
    int h1 = rem / 10, w1 = rem - h1 * 10;
    int tc = tok / 72, tr = tok - tc * 72;
    int th = tr / 12, tw = tr - th * 12;
    int cs = c1 * 2 + tc, hs = h1 * 6 + th, wsp = w1 * 12 + tw;
    int co = (cs + 1) & 3;
    int ho = hs + 3; if (ho >= 60) ho -= 60;
    int wo = wsp + 6; if (wo >= 120) wo -= 120;
    src = ((size_t)b * 28800 + (co * 60 + ho) * 120 + wo) * 512;
  } else {
    src = (size_t)t * 512;
  }
  const float4* xr = (const float4*)(x + src);
  float4 v0 = xr[l * 2], v1 = xr[l * 2 + 1];
  float s = v0.x + v0.y + v0.z + v0.w + v1.x + v1.y + v1.z + v1.w;
  float s2 = v0.x * v0.x + v0.y * v0.y + v0.z * v0.z + v0.w * v0.w +
             v1.x * v1.x + v1.y * v1.y + v1.z * v1.z + v1.w * v1.w;
  #pragma unroll
  for (int o2 = 32; o2; o2 >>= 1) {
    s += __shfl_xor(s, o2);
    s2 += __shfl_xor(s2, o2);
  }
  float mean = s * (1.0f / 512.0f);
  float var = s2 * (1.0f / 512.0f) - mean * mean;
  float inv = rsqrtf(var + 1e-6f);
  const float4* scp = (const float4*)sc;
  const float4* bip = (const float4*)bi;
  float4 sa = scp[l * 2], sb = scp[l * 2 + 1];
  float4 ba = bip[l * 2], bb = bip[l * 2 + 1];
  u16x8 ov;
  ov[0] = f2bf((v0.x - mean) * inv * sa.x + ba.x);
  ov[1] = f2bf((v0.y - mean) * inv * sa.y + ba.y);
  ov[2] = f2bf((v0.z - mean) * inv * sa.z + ba.z);
  ov[3] = f2bf((v0.w - mean) * inv * sa.w + ba.w);
  ov[4] = f2bf((v1.x - mean) * inv * sb.x + bb.x);
  ov[5] = f2bf((v1.y - mean) * inv * sb.y + bb.y);
  ov[6] = f2bf((v1.z - mean) * inv * sb.z + bb.z);
  ov[7] = f2bf((v1.w - mean) * inv * sb.w + bb.w);
  *(u16x8*)&o[(size_t)t * 512 + l * 8] = ov;
}

// ---------------- bf16 MFMA GEMM, 128x128 tile, BK=32 -----------------------
// A: M x K row-major bf16.  Bt: N x K row-major bf16 (i.e. B transposed).
// EPI 0: qkv scatter -> bf16 [win][3][head][tok][dh]
// EPI 1: proj: window-reverse + unshift + residual -> f32 d_out
// EPI 2: gelu -> bf16 mid
// EPI 3: accumulate into f32 d_out
template <int EPI>
__launch_bounds__(256)
__global__ void gemm128(const unsigned short* __restrict__ A,
                        const unsigned short* __restrict__ Bt,
                        const float* __restrict__ bias, void* __restrict__ outp,
                        const float* __restrict__ res, int M, int N, int K) {
  __shared__ __attribute__((aligned(16))) unsigned short As[128 * 32];
  __shared__ __attribute__((aligned(16))) unsigned short Bs[128 * 32];
  int tid = threadIdx.x;
  int w = tid >> 6, l = tid & 63;
  int ntile = N >> 7;
  int bm = blockIdx.x / ntile, bn = blockIdx.x - bm * ntile;
  const unsigned short* Ab = A + (size_t)bm * 128 * K;
  const unsigned short* Bb = Bt + (size_t)bn * 128 * K;
  int lr = l >> 2, lc = (l & 3) << 3;
  int lane15 = l & 15, lk = (l >> 4) << 3;
  int wr = (w >> 1) << 6, wc = (w & 1) << 6;
  f32x4 acc[4][4] = {};
  for (int k0 = 0; k0 < K; k0 += 32) {
    #pragma unroll
    for (int i = 0; i < 2; ++i) {
      int row = i * 64 + w * 16 + lr;
      gload_lds16(Ab + (size_t)row * K + k0 + lc, &As[(i * 64 + w * 16) * 32]);
      gload_lds16(Bb + (size_t)row * K + k0 + lc, &Bs[(i * 64 + w * 16) * 32]);
    }
    __syncthreads();
    bf16x8 af[4], bf[4];
    #pragma unroll
    for (int mt = 0; mt < 4; ++mt)
      af[mt] = *(const bf16x8*)&As[(wr + mt * 16 + lane15) * 32 + lk];
    #pragma unroll
    for (int nt = 0; nt < 4; ++nt)
      bf[nt] = *(const bf16x8*)&Bs[(wc + nt * 16 + lane15) * 32 + lk];
    #pragma unroll
    for (int mt = 0; mt < 4; ++mt)
      #pragma unroll
      for (int nt = 0; nt < 4; ++nt)
        acc[mt][nt] =
            __builtin_amdgcn_mfma_f32_16x16x32_bf16(af[mt], bf[nt], acc[mt][nt], 0, 0, 0);
    __syncthreads();
  }
  float* outf = (float*)outp;
  unsigned short* outh = (unsigned short*)outp;
  #pragma unroll
  for (int mt = 0; mt < 4; ++mt) {
    #pragma unroll
    for (int j = 0; j < 4; ++j) {
      int grow = bm * 128 + wr + mt * 16 + ((l >> 4) << 2) + j;
      int win = 0, tok = 0;
      size_t rowbase = 0;
      if constexpr (EPI == 0) {
        win = grow / 144;
        tok = grow - win * 144;
      } else if constexpr (EPI == 1) {
        win = grow / 144;
        tok = grow - win * 144;
        int b = win / 200, wl = win - b * 200;
        int c1 = wl / 100, rem = wl - c1 * 100;
        int h1 = rem / 10, w1 = rem - h1 * 10;
        int tc = tok / 72, tr = tok - tc * 72;
        int th = tr / 12, tw = tr - th * 12;
        int cs = c1 * 2 + tc, hs = h1 * 6 + th, wsp = w1 * 12 + tw;
        int co = (cs + 1) & 3;
        int ho = hs + 3; if (ho >= 60) ho -= 60;
        int wo = wsp + 6; if (wo >= 120) wo -= 120;
        rowbase = ((size_t)b * 28800 + (co * 60 + ho) * 120 + wo) * 512;
      }
      #pragma unroll
      for (int nt = 0; nt < 4; ++nt) {
        int gcol = bn * 128 + wc + nt * 16 + lane15;
        float val = acc[mt][nt][j] + bias[gcol];
        if constexpr (EPI == 0) {
          int which = gcol >> 9, hd = (gcol >> 6) & 7, dh = gcol & 63;
          outh[(((size_t)(win * 3 + which) * 8 + hd) * 144 + tok) * 64 + dh] = f2bf(val);
        } else if constexpr (EPI == 1) {
          size_t oi = rowbase + gcol;
          outf[oi] = res[oi] + val;
        } else if constexpr (EPI == 2) {
          float u = 0.7978845608f * (val + 0.044715f * val * val * val);
          float g = 0.5f * val * (1.0f + tanhf(u));
          outh[(size_t)grow * N + gcol] = f2bf(g);
        } else {
          size_t oi = (size_t)grow * N + gcol;
          outf[oi] += val;
        }
      }
    }
  }
}

// ---------------- attention: one block per (window, head) -------------------
// 9 waves x 16 Q-rows.  K in LDS stride 72, V transposed in LDS stride 168,
// P via LDS (K-dim padded 144->160 with zeros).
__launch_bounds__(576)
__global__ void attn_k(const unsigned short* __restrict__ qkv,
                       unsigned short* __restrict__ owin) {
  __shared__ __attribute__((aligned(16))) unsigned short Ks[144 * 72];
  __shared__ __attribute__((aligned(16))) unsigned short Vt[64 * 168];
  __shared__ __attribute__((aligned(16))) unsigned short Ps[144 * 168];
  __shared__ unsigned char gid[144];
  int bid = blockIdx.x;
  int win = bid >> 3, head = bid & 7;
  const unsigned short* qb = qkv + ((size_t)(win * 3 + 0) * 8 + head) * (144 * 64);
  const unsigned short* kb = qkv + ((size_t)(win * 3 + 1) * 8 + head) * (144 * 64);
  const unsigned short* vb = qkv + ((size_t)(win * 3 + 2) * 8 + head) * (144 * 64);
  int tid = threadIdx.x;
  {
    int row = tid >> 2, c0 = (tid & 3) << 4;
    u16x8 ka = *(const u16x8*)(kb + row * 64 + c0);
    u16x8 kc = *(const u16x8*)(kb + row * 64 + c0 + 8);
    *(u16x8*)&Ks[row * 72 + c0] = ka;
    *(u16x8*)&Ks[row * 72 + c0 + 8] = kc;
    u16x8 va = *(const u16x8*)(vb + row * 64 + c0);
    u16x8 vc = *(const u16x8*)(vb + row * 64 + c0 + 8);
    #pragma unroll
    for (int j = 0; j < 8; ++j) Vt[(c0 + j) * 168 + row] = va[j];
    #pragma unroll
    for (int j = 0; j < 8; ++j) Vt[(c0 + 8 + j) * 168 + row] = vc[j];
  }
  for (int i = tid; i < 64 * 24; i += 576) {
    int d = i / 24, m = i - d * 24;
    Vt[d * 168 + 144 + m] = 0;
  }
  for (int i = tid; i < 144 * 24; i += 576) {
    int r = i / 24, c = i - r * 24;
    Ps[r * 168 + 144 + c] = 0;
  }
  if (tid < 144) {
    int wl = win % 200;
    int c1 = wl / 100, rem = wl - c1 * 100;
    int h1 = rem / 10, w1 = rem - h1 * 10;
    int tc = tid / 72, tr = tid - tc * 72;
    int th = tr / 12, tw = tr - th * 12;
    int cs = c1 * 2 + tc, hs = h1 * 6 + th, wsp = w1 * 12 + tw;
    int rc = cs < 2 ? 0 : (cs < 3 ? 1 : 2);
    int rh = hs < 54 ? 0 : (hs < 57 ? 1 : 2);
    int rw = wsp < 108 ? 0 : (wsp < 114 ? 1 : 2);
    if (rw == 1) rw = 2;
    gid[tid] = (unsigned char)(rc * 9 + rh * 3 + rw);
  }
  __syncthreads();
  int wv = tid >> 6, l = tid & 63;
  int lane15 = l & 15, lk = (l >> 4) << 3;
  bf16x8 aq0 = *(const bf16x8*)(qb + (wv * 16 + lane15) * 64 + lk);
  bf16x8 aq1 = *(const bf16x8*)(qb + (wv * 16 + lane15) * 64 + 32 + lk);
  f32x4 sf[9];
  #pragma unroll
  for (int ct = 0; ct < 9; ++ct) {
    f32x4 z = {};
    bf16x8 b0 = *(const bf16x8*)&Ks[(ct * 16 + lane15) * 72 + lk];
    bf16x8 b1 = *(const bf16x8*)&Ks[(ct * 16 + lane15) * 72 + 32 + lk];
    z = __builtin_amdgcn_mfma_f32_16x16x32_bf16(aq0, b0, z, 0, 0, 0);
    z = __builtin_amdgcn_mfma_f32_16x16x32_bf16(aq1, b1, z, 0, 0, 0);
    sf[ct] = z;
  }
  int gi[4];
  #pragma unroll
  for (int j = 0; j < 4; ++j) gi[j] = gid[wv * 16 + ((l >> 4) << 2) + j];
  float mx[4] = {-1e30f, -1e30f, -1e30f, -1e30f};
  #pragma unroll
  for (int ct = 0; ct < 9; ++ct) {
    int gj = gid[ct * 16 + lane15];
    #pragma unroll
    for (int j = 0; j < 4; ++j) {
      float s = sf[ct][j] * 0.125f;
      if (gj != gi[j]) s = -1e30f;
      sf[ct][j] = s;
      mx[j] = fmaxf(mx[j], s);
    }
  }
  #pragma unroll
  for (int o2 = 8; o2; o2 >>= 1)
    #pragma unroll
    for (int j = 0; j < 4; ++j) mx[j] = fmaxf(mx[j], __shfl_xor(mx[j], o2));
  float sm[4] = {0.f, 0.f, 0.f, 0.f};
  #pragma unroll
  for (int ct = 0; ct < 9; ++ct)
    #pragma unroll
    for (int j = 0; j < 4; ++j) {
      float e = __expf(sf[ct][j] - mx[j]);
      sf[ct][j] = e;
      sm[j] += e;
    }
  #pragma unroll
  for (int o2 = 8; o2; o2 >>= 1)
    #pragma unroll
    for (int j = 0; j < 4; ++j) sm[j] += __shfl_xor(sm[j], o2);
  float rs[4];
  #pragma unroll
  for (int j = 0; j < 4; ++j) rs[j] = 1.0f / sm[j];
  #pragma unroll
  for (int ct = 0; ct < 9; ++ct)
    #pragma unroll
    for (int j = 0; j < 4; ++j)
      Ps[(wv * 16 + ((l >> 4) << 2) + j) * 168 + ct * 16 + lane15] =
          f2bf(sf[ct][j] * rs[j]);
  __syncthreads();
  f32x4 of[4] = {};
  #pragma unroll
  for (int ks = 0; ks < 5; ++ks) {
    bf16x8 ap = *(const bf16x8*)&Ps[(wv * 16 + lane15) * 168 + ks * 32 + lk];
    #pragma unroll
    for (int nt = 0; nt < 4; ++nt) {
      bf16x8 bv = *(const bf16x8*)&Vt[(nt * 16 + lane15) * 168 + ks * 32 + lk];
      of[nt] = __builtin_amdgcn_mfma_f32_16x16x32_bf16(ap, bv, of[nt], 0, 0, 0);
    }
  }
  unsigned short* ob = owin + (size_t)win * 144 * 512 + head * 64;
  #pragma unroll
  for (int nt = 0; nt < 4; ++nt)
    #pragma unroll
    for (int j = 0; j < 4; ++j) {
      int row = wv * 16 + ((l >> 4) << 2) + j;
      ob[(size_t)row * 512 + nt * 16 + lane15] = f2bf(of[nt][j]);
    }
}

extern "C" void kernel_launch(void* const* d_in, const int* in_sizes, int n_in,
                              void* d_out, int out_size, void* d_ws, size_t ws_size,
                              hipStream_t stream) {
  const float* x = (const float*)d_in[0];
  const float* qkv_w = (const float*)d_in[1];
  const float* qkv_b = (const float*)d_in[2];
  const float* proj_w = (const float*)d_in[3];
  const float* proj_b = (const float*)d_in[4];
  const float* n1s = (const float*)d_in[5];
  const float* n1b = (const float*)d_in[6];
  const float* n2s = (const float*)d_in[7];
  const float* n2b = (const float*)d_in[8];
  const float* w1 = (const float*)d_in[9];
  const float* b1 = (const float*)d_in[10];
  const float* w2 = (const float*)d_in[11];
  const float* b2 = (const float*)d_in[12];
  float* out = (float*)d_out;
  char* ws = (char*)d_ws;

  unsigned short* WqT = (unsigned short*)(ws);               // 1536x512
  unsigned short* WpT = (unsigned short*)(ws + 1572864);     // 512x512
  unsigned short* W1T = (unsigned short*)(ws + 2097152);     // 2048x512
  unsigned short* W2T = (unsigned short*)(ws + 4194304);     // 512x2048
  unsigned short* hwin = (unsigned short*)(ws + 6291456);    // 57600x512 (also ln2out)
  unsigned short* qkvb = (unsigned short*)(ws + 65273856);   // 57600x1536
  unsigned short* owin = (unsigned short*)(ws + 242221056);  // 57600x512
  unsigned short* mid = qkvb;                                // 57600x2048 (aliases qkv+owin)

  wtrans<<<(512 * 1536 + 255) / 256, 256, 0, stream>>>(qkv_w, WqT, 512, 1536);
  wtrans<<<(512 * 512 + 255) / 256, 256, 0, stream>>>(proj_w, WpT, 512, 512);
  wtrans<<<(512 * 2048 + 255) / 256, 256, 0, stream>>>(w1, W1T, 512, 2048);
  wtrans<<<(2048 * 512 + 255) / 256, 256, 0, stream>>>(w2, W2T, 2048, 512);
  ln_k<0><<<14400, 256, 0, stream>>>(x, n1s, n1b, hwin);
  gemm128<0><<<450 * 12, 256, 0, stream>>>(hwin, WqT, qkv_b, qkvb, nullptr, 57600, 1536, 512);
  attn_k<<<3200, 576, 0, stream>>>(qkvb, owin);
  gemm128<1><<<450 * 4, 256, 0, stream>>>(owin, WpT, proj_b, out, x, 57600, 512, 512);
  ln_k<1><<<14400, 256, 0, stream>>>(out, n2s, n2b, hwin);
  gemm128<2><<<450 * 16, 256, 0, stream>>>(hwin, W1T, b1, mid, nullptr, 57600, 2048, 512);
  gemm128<3><<<450 * 4, 256, 0, stream>>>(mid, W2T, b2, out, nullptr, 57600, 512, 2048);
}

// Round 2
// 933.320 us; speedup vs baseline: 1.0191x; 1.0191x over previous
//
#include <hip/hip_runtime.h>

typedef __attribute__((ext_vector_type(8))) short bf16x8;
typedef __attribute__((ext_vector_type(4))) float f32x4;
typedef __attribute__((ext_vector_type(8))) unsigned short u16x8;

#define BARX() asm volatile("s_barrier" ::: "memory")
#define VMC(n) asm volatile("s_waitcnt vmcnt(" #n ")" ::: "memory")

__device__ inline unsigned short f2bf(float f) {
  unsigned int u = __float_as_uint(f);
  u += 0x7fffu + ((u >> 16) & 1u);
  return (unsigned short)(u >> 16);
}

__device__ inline void gload_lds16(const void* g, void* l) {
  __builtin_amdgcn_global_load_lds(
      (const __attribute__((address_space(1))) void*)g,
      (__attribute__((address_space(3))) void*)l, 16, 0, 0);
}

// ---------------- weight transpose + bf16 cast: W[K][N] -> Wt[N][K] ----------
__global__ void wtrans(const float* __restrict__ W, unsigned short* __restrict__ Wt,
                       int K, int N) {
  int idx = blockIdx.x * 256 + threadIdx.x;
  if (idx >= K * N) return;
  int k = idx / N, n = idx - k * N;
  Wt[(size_t)n * K + k] = f2bf(W[idx]);
}

// ---------------- LayerNorm (+ optional shift/window gather), f32 -> bf16 ----
template <int MODE>
__global__ void ln_k(const float* __restrict__ x, const float* __restrict__ sc,
                     const float* __restrict__ bi, unsigned short* __restrict__ o) {
  int t = blockIdx.x * 4 + (threadIdx.x >> 6);
  int l = threadIdx.x & 63;
  size_t src;
  if (MODE == 0) {
    int b = t / 28800, r = t - b * 28800;
    int win = r / 144, tok = r - win * 144;
    int c1 = win / 100, rem = win - c1 * 100;
    int h1 = rem / 10, w1 = rem - h1 * 10;
    int tc = tok / 72, tr = tok - tc * 72;
    int th = tr / 12, tw = tr - th * 12;
    int cs = c1 * 2 + tc, hs = h1 * 6 + th, wsp = w1 * 12 + tw;
    int co = (cs + 1) & 3;
    int ho = hs + 3; if (ho >= 60) ho -= 60;
    int wo = wsp + 6; if (wo >= 120) wo -= 120;
    src = ((size_t)b * 28800 + (co * 60 + ho) * 120 + wo) * 512;
  } else {
    src = (size_t)t * 512;
  }
  const float4* xr = (const float4*)(x + src);
  float4 v0 = xr[l * 2], v1 = xr[l * 2 + 1];
  float s = v0.x + v0.y + v0.z + v0.w + v1.x + v1.y + v1.z + v1.w;
  float s2 = v0.x * v0.x + v0.y * v0.y + v0.z * v0.z + v0.w * v0.w +
             v1.x * v1.x + v1.y * v1.y + v1.z * v1.z + v1.w * v1.w;
  #pragma unroll
  for (int o2 = 32; o2; o2 >>= 1) {
    s += __shfl_xor(s, o2);
    s2 += __shfl_xor(s2, o2);
  }
  float mean = s * (1.0f / 512.0f);
  float var = s2 * (1.0f / 512.0f) - mean * mean;
  float inv = rsqrtf(var + 1e-6f);
  const float4* scp = (const float4*)sc;
  const float4* bip = (const float4*)bi;
  float4 sa = scp[l * 2], sb = scp[l * 2 + 1];
  float4 ba = bip[l * 2], bb = bip[l * 2 + 1];
  u16x8 ov;
  ov[0] = f2bf((v0.x - mean) * inv * sa.x + ba.x);
  ov[1] = f2bf((v0.y - mean) * inv * sa.y + ba.y);
  ov[2] = f2bf((v0.z - mean) * inv * sa.z + ba.z);
  ov[3] = f2bf((v0.w - mean) * inv * sa.w + ba.w);
  ov[4] = f2bf((v1.x - mean) * inv * sb.x + bb.x);
  ov[5] = f2bf((v1.y - mean) * inv * sb.y + bb.y);
  ov[6] = f2bf((v1.z - mean) * inv * sb.z + bb.z);
  ov[7] = f2bf((v1.w - mean) * inv * sb.w + bb.w);
  *(u16x8*)&o[(size_t)t * 512 + l * 8] = ov;
}

// ---------------- 256x256 bf16 MFMA GEMM, K-chunked 4-phase pipeline ---------
// A: M x K row-major bf16.  Bt: N x K row-major bf16.
// chunk c = K-slice of 32: A[256][32] + B[256][32] in slot c%4 (128 KiB LDS).
// 4 phases per K-tile (BK=64): (mq,ks) in (0,0),(1,0),(0,1),(1,1).
// Steady state: stage 1 half-chunk (2 x global_load_lds16) per phase,
// s_waitcnt vmcnt(8) twice per K-tile (2-chunk lead), raw s_barrier.
// XOR swizzle col ^= ((row>>1)&3)<<3 on both stage-source and ds_read.
template <int EPI>
__launch_bounds__(512, 2)
__global__ void gemm256(const unsigned short* __restrict__ A,
                        const unsigned short* __restrict__ Bt,
                        const float* __restrict__ bias, void* __restrict__ outp,
                        const float* __restrict__ res, int M, int N, int K) {
  __shared__ __attribute__((aligned(16))) unsigned short lds[4][2][8192];
  const int tid = threadIdx.x;
  const int w = tid >> 6, l = tid & 63;
  const int wm = w >> 2, wn = w & 3;
  const int lane15 = l & 15, lk = (l >> 4) << 3;
  const int ntile = N >> 8;
  const int bm = blockIdx.x / ntile, bn = blockIdx.x - bm * ntile;
  const int KT = K >> 6;
  const unsigned short* Ag = A + (size_t)bm * 256 * K;
  const unsigned short* Bg = Bt + (size_t)bn * 256 * K;
  const int lq = l >> 2;
  const int sc0 = (l & 3) << 3;

  f32x4 acc[8][4] = {};

  auto STAGE = [&](int c, int part) {
    const unsigned short* gb = part ? Bg : Ag;
    unsigned short* lb = (unsigned short*)&lds[c & 3][part][0];
    const int kc = c << 5;
    #pragma unroll
    for (int i = 0; i < 2; ++i) {
      int j = i * 8 + w;
      int row = j * 16 + lq;
      int sc = sc0 ^ (((row >> 1) & 3) << 3);
      gload_lds16(gb + (size_t)row * K + kc + sc, lb + j * 512);
    }
  };
  auto LDA4 = [&](bf16x8* af, int c, int mq) {
    const unsigned short* p = &lds[c & 3][0][0];
    #pragma unroll
    for (int mf = 0; mf < 4; ++mf) {
      int row = wm * 128 + (mq * 4 + mf) * 16 + lane15;
      af[mf] = *(const bf16x8*)&p[row * 32 + (lk ^ (((row >> 1) & 3) << 3))];
    }
  };
  auto LDB4 = [&](bf16x8* bfr, int c) {
    const unsigned short* p = &lds[c & 3][1][0];
    #pragma unroll
    for (int nf = 0; nf < 4; ++nf) {
      int row = wn * 64 + nf * 16 + lane15;
      bfr[nf] = *(const bf16x8*)&p[row * 32 + (lk ^ (((row >> 1) & 3) << 3))];
    }
  };
  auto MFMA16 = [&](bf16x8* af, bf16x8* bfr, int mq) {
    __builtin_amdgcn_s_setprio(1);
    #pragma unroll
    for (int mf = 0; mf < 4; ++mf)
      #pragma unroll
      for (int nf = 0; nf < 4; ++nf)
        acc[mq * 4 + mf][nf] = __builtin_amdgcn_mfma_f32_16x16x32_bf16(
            af[mf], bfr[nf], acc[mq * 4 + mf][nf], 0, 0, 0);
    __builtin_amdgcn_s_setprio(0);
  };

  // prologue: chunks 0,1,2 in flight; need chunk 0 resident (<=8 outstanding)
  STAGE(0, 0); STAGE(0, 1); STAGE(1, 0); STAGE(1, 1); STAGE(2, 0); STAGE(2, 1);
  VMC(8);
  BARX();

  for (int t = 0; t < KT; ++t) {
    const int c0 = 2 * t, c1 = c0 + 1;
    const bool s01 = (t <= KT - 2), s23 = (t <= KT - 3);
    bf16x8 af[4], bfr[4];
    // phase 0: (mq0, ks0)
    LDA4(af, c0, 0); LDB4(bfr, c0);
    if (s01) STAGE(c0 + 3, 0);
    BARX();
    MFMA16(af, bfr, 0);
    BARX();
    // phase 1: (mq1, ks0)
    LDA4(af, c0, 1);
    if (s01) STAGE(c0 + 3, 1);
    BARX();
    MFMA16(af, bfr, 1);
    if (t <= KT - 2) { VMC(8); } else { VMC(0); }
    BARX();
    // phase 2: (mq0, ks1)
    LDA4(af, c1, 0); LDB4(bfr, c1);
    if (s23) STAGE(c0 + 4, 0);
    BARX();
    MFMA16(af, bfr, 0);
    BARX();
    // phase 3: (mq1, ks1)
    LDA4(af, c1, 1);
    if (s23) STAGE(c0 + 4, 1);
    BARX();
    MFMA16(af, bfr, 1);
    if (s23) { VMC(8); } else if (t == KT - 2) { VMC(4); }
    BARX();
  }

  // ---------------- epilogue ----------------
  float* outf = (float*)outp;
  unsigned short* outh = (unsigned short*)outp;
  #pragma unroll
  for (int mi = 0; mi < 8; ++mi) {
    #pragma unroll
    for (int j = 0; j < 4; ++j) {
      int grow = bm * 256 + wm * 128 + mi * 16 + ((l >> 4) << 2) + j;
      int win = 0, tok = 0;
      size_t rowbase = 0;
      if constexpr (EPI == 0) {
        win = grow / 144;
        tok = grow - win * 144;
      } else if constexpr (EPI == 1) {
        win = grow / 144;
        tok = grow - win * 144;
        int b = win / 200, wl = win - b * 200;
        int c1 = wl / 100, rem = wl - c1 * 100;
        int h1 = rem / 10, w1 = rem - h1 * 10;
        int tc = tok / 72, tr = tok - tc * 72;
        int th = tr / 12, tw = tr - th * 12;
        int cs = c1 * 2 + tc, hs = h1 * 6 + th, wsp = w1 * 12 + tw;
        int co = (cs + 1) & 3;
        int ho = hs + 3; if (ho >= 60) ho -= 60;
        int wo = wsp + 6; if (wo >= 120) wo -= 120;
        rowbase = ((size_t)b * 28800 + (co * 60 + ho) * 120 + wo) * 512;
      }
      #pragma unroll
      for (int nf = 0; nf < 4; ++nf) {
        int gcol = bn * 256 + wn * 64 + nf * 16 + lane15;
        float val = acc[mi][nf][j] + bias[gcol];
        if constexpr (EPI == 0) {
          int which = gcol >> 9, hd = (gcol >> 6) & 7, dh = gcol & 63;
          outh[(((size_t)(win * 3 + which) * 8 + hd) * 144 + tok) * 64 + dh] = f2bf(val);
        } else if constexpr (EPI == 1) {
          size_t oi = rowbase + gcol;
          outf[oi] = res[oi] + val;
        } else if constexpr (EPI == 2) {
          float u = 0.7978845608f * (val + 0.044715f * val * val * val);
          float g = val / (1.0f + __expf(-2.0f * u));  // exact tanh-gelu identity
          outh[(size_t)grow * N + gcol] = f2bf(g);
        } else {
          size_t oi = (size_t)grow * N + gcol;
          outf[oi] += val;
        }
      }
    }
  }
}

// ---------------- attention: one block per (window, head) -------------------
__launch_bounds__(576)
__global__ void attn_k(const unsigned short* __restrict__ qkv,
                       unsigned short* __restrict__ owin) {
  __shared__ __attribute__((aligned(16))) unsigned short Ks[144 * 72];
  __shared__ __attribute__((aligned(16))) unsigned short Vt[64 * 168];
  __shared__ __attribute__((aligned(16))) unsigned short Ps[144 * 168];
  __shared__ unsigned char gid[144];
  int bid = blockIdx.x;
  int win = bid >> 3, head = bid & 7;
  const unsigned short* qb = qkv + ((size_t)(win * 3 + 0) * 8 + head) * (144 * 64);
  const unsigned short* kb = qkv + ((size_t)(win * 3 + 1) * 8 + head) * (144 * 64);
  const unsigned short* vb = qkv + ((size_t)(win * 3 + 2) * 8 + head) * (144 * 64);
  int tid = threadIdx.x;
  {
    int row = tid >> 2, c0 = (tid & 3) << 4;
    u16x8 ka = *(const u16x8*)(kb + row * 64 + c0);
    u16x8 kc = *(const u16x8*)(kb + row * 64 + c0 + 8);
    *(u16x8*)&Ks[row * 72 + c0] = ka;
    *(u16x8*)&Ks[row * 72 + c0 + 8] = kc;
    u16x8 va = *(const u16x8*)(vb + row * 64 + c0);
    u16x8 vc = *(const u16x8*)(vb + row * 64 + c0 + 8);
    #pragma unroll
    for (int j = 0; j < 8; ++j) Vt[(c0 + j) * 168 + row] = va[j];
    #pragma unroll
    for (int j = 0; j < 8; ++j) Vt[(c0 + 8 + j) * 168 + row] = vc[j];
  }
  for (int i = tid; i < 64 * 24; i += 576) {
    int d = i / 24, m = i - d * 24;
    Vt[d * 168 + 144 + m] = 0;
  }
  for (int i = tid; i < 144 * 24; i += 576) {
    int r = i / 24, c = i - r * 24;
    Ps[r * 168 + 144 + c] = 0;
  }
  if (tid < 144) {
    int wl = win % 200;
    int c1 = wl / 100, rem = wl - c1 * 100;
    int h1 = rem / 10, w1 = rem - h1 * 10;
    int tc = tid / 72, tr = tid - tc * 72;
    int th = tr / 12, tw = tr - th * 12;
    int cs = c1 * 2 + tc, hs = h1 * 6 + th, wsp = w1 * 12 + tw;
    int rc = cs < 2 ? 0 : (cs < 3 ? 1 : 2);
    int rh = hs < 54 ? 0 : (hs < 57 ? 1 : 2);
    int rw = wsp < 108 ? 0 : (wsp < 114 ? 1 : 2);
    if (rw == 1) rw = 2;
    gid[tid] = (unsigned char)(rc * 9 + rh * 3 + rw);
  }
  __syncthreads();
  int wv = tid >> 6, l = tid & 63;
  int lane15 = l & 15, lk = (l >> 4) << 3;
  bf16x8 aq0 = *(const bf16x8*)(qb + (wv * 16 + lane15) * 64 + lk);
  bf16x8 aq1 = *(const bf16x8*)(qb + (wv * 16 + lane15) * 64 + 32 + lk);
  f32x4 sf[9];
  #pragma unroll
  for (int ct = 0; ct < 9; ++ct) {
    f32x4 z = {};
    bf16x8 b0 = *(const bf16x8*)&Ks[(ct * 16 + lane15) * 72 + lk];
    bf16x8 b1 = *(const bf16x8*)&Ks[(ct * 16 + lane15) * 72 + 32 + lk];
    z = __builtin_amdgcn_mfma_f32_16x16x32_bf16(aq0, b0, z, 0, 0, 0);
    z = __builtin_amdgcn_mfma_f32_16x16x32_bf16(aq1, b1, z, 0, 0, 0);
    sf[ct] = z;
  }
  int gi[4];
  #pragma unroll
  for (int j = 0; j < 4; ++j) gi[j] = gid[wv * 16 + ((l >> 4) << 2) + j];
  float mx[4] = {-1e30f, -1e30f, -1e30f, -1e30f};
  #pragma unroll
  for (int ct = 0; ct < 9; ++ct) {
    int gj = gid[ct * 16 + lane15];
    #pragma unroll
    for (int j = 0; j < 4; ++j) {
      float s = sf[ct][j] * 0.125f;
      if (gj != gi[j]) s = -1e30f;
      sf[ct][j] = s;
      mx[j] = fmaxf(mx[j], s);
    }
  }
  #pragma unroll
  for (int o2 = 8; o2; o2 >>= 1)
    #pragma unroll
    for (int j = 0; j < 4; ++j) mx[j] = fmaxf(mx[j], __shfl_xor(mx[j], o2));
  float sm[4] = {0.f, 0.f, 0.f, 0.f};
  #pragma unroll
  for (int ct = 0; ct < 9; ++ct)
    #pragma unroll
    for (int j = 0; j < 4; ++j) {
      float e = __expf(sf[ct][j] - mx[j]);
      sf[ct][j] = e;
      sm[j] += e;
    }
  #pragma unroll
  for (int o2 = 8; o2; o2 >>= 1)
    #pragma unroll
    for (int j = 0; j < 4; ++j) sm[j] += __shfl_xor(sm[j], o2);
  float rs[4];
  #pragma unroll
  for (int j = 0; j < 4; ++j) rs[j] = 1.0f / sm[j];
  #pragma unroll
  for (int ct = 0; ct < 9; ++ct)
    #pragma unroll
    for (int j = 0; j < 4; ++j)
      Ps[(wv * 16 + ((l >> 4) << 2) + j) * 168 + ct * 16 + lane15] =
          f2bf(sf[ct][j] * rs[j]);
  __syncthreads();
  f32x4 of[4] = {};
  #pragma unroll
  for (int ks = 0; ks < 5; ++ks) {
    bf16x8 ap = *(const bf16x8*)&Ps[(wv * 16 + lane15) * 168 + ks * 32 + lk];
    #pragma unroll
    for (int nt = 0; nt < 4; ++nt) {
      bf16x8 bv = *(const bf16x8*)&Vt[(nt * 16 + lane15) * 168 + ks * 32 + lk];
      of[nt] = __builtin_amdgcn_mfma_f32_16x16x32_bf16(ap, bv, of[nt], 0, 0, 0);
    }
  }
  unsigned short* ob = owin + (size_t)win * 144 * 512 + head * 64;
  #pragma unroll
  for (int nt = 0; nt < 4; ++nt)
    #pragma unroll
    for (int j = 0; j < 4; ++j) {
      int row = wv * 16 + ((l >> 4) << 2) + j;
      ob[(size_t)row * 512 + nt * 16 + lane15] = f2bf(of[nt][j]);
    }
}

extern "C" void kernel_launch(void* const* d_in, const int* in_sizes, int n_in,
                              void* d_out, int out_size, void* d_ws, size_t ws_size,
                              hipStream_t stream) {
  const float* x = (const float*)d_in[0];
  const float* qkv_w = (const float*)d_in[1];
  const float* qkv_b = (const float*)d_in[2];
  const float* proj_w = (const float*)d_in[3];
  const float* proj_b = (const float*)d_in[4];
  const float* n1s = (const float*)d_in[5];
  const float* n1b = (const float*)d_in[6];
  const float* n2s = (const float*)d_in[7];
  const float* n2b = (const float*)d_in[8];
  const float* w1 = (const float*)d_in[9];
  const float* b1 = (const float*)d_in[10];
  const float* w2 = (const float*)d_in[11];
  const float* b2 = (const float*)d_in[12];
  float* out = (float*)d_out;
  char* ws = (char*)d_ws;

  unsigned short* WqT = (unsigned short*)(ws);               // 1536x512
  unsigned short* WpT = (unsigned short*)(ws + 1572864);     // 512x512
  unsigned short* W1T = (unsigned short*)(ws + 2097152);     // 2048x512
  unsigned short* W2T = (unsigned short*)(ws + 4194304);     // 512x2048
  unsigned short* hwin = (unsigned short*)(ws + 6291456);    // 57600x512 (also ln2out)
  unsigned short* qkvb = (unsigned short*)(ws + 65273856);   // 57600x1536
  unsigned short* owin = (unsigned short*)(ws + 242221056);  // 57600x512
  unsigned short* mid = qkvb;                                // 57600x2048 (aliases qkv+owin)

  wtrans<<<(512 * 1536 + 255) / 256, 256, 0, stream>>>(qkv_w, WqT, 512, 1536);
  wtrans<<<(512 * 512 + 255) / 256, 256, 0, stream>>>(proj_w, WpT, 512, 512);
  wtrans<<<(512 * 2048 + 255) / 256, 256, 0, stream>>>(w1, W1T, 512, 2048);
  wtrans<<<(2048 * 512 + 255) / 256, 256, 0, stream>>>(w2, W2T, 2048, 512);
  ln_k<0><<<14400, 256, 0, stream>>>(x, n1s, n1b, hwin);
  gemm256<0><<<225 * 6, 512, 0, stream>>>(hwin, WqT, qkv_b, qkvb, nullptr, 57600, 1536, 512);
  attn_k<<<3200, 576, 0, stream>>>(qkvb, owin);
  gemm256<1><<<225 * 2, 512, 0, stream>>>(owin, WpT, proj_b, out, x, 57600, 512, 512);
  ln_k<1><<<14400, 256, 0, stream>>>(out, n2s, n2b, hwin);
  gemm256<2><<<225 * 8, 512, 0, stream>>>(hwin, W1T, b1, mid, nullptr, 57600, 2048, 512);
  gemm256<3><<<225 * 2, 512, 0, stream>>>(mid, W2T, b2, out, nullptr, 57600, 512, 2048);
}

// Round 3
// 881.535 us; speedup vs baseline: 1.0789x; 1.0587x over previous
//
#include <hip/hip_runtime.h>

typedef __attribute__((ext_vector_type(8))) short bf16x8;
typedef __attribute__((ext_vector_type(4))) float f32x4;
typedef __attribute__((ext_vector_type(8))) unsigned short u16x8;

#define BAR() __builtin_amdgcn_s_barrier()
#define VMC(n) asm volatile("s_waitcnt vmcnt(" #n ")" ::: "memory")
#define WAITL() do { asm volatile("s_waitcnt lgkmcnt(0)"); __builtin_amdgcn_sched_barrier(0); } while (0)
#define DSR(dst, a, off) asm volatile("ds_read_b128 %0, %1 offset:" #off : "=&v"(dst) : "v"(a))

__device__ inline unsigned short f2bf(float f) {
  unsigned int u = __float_as_uint(f);
  u += 0x7fffu + ((u >> 16) & 1u);
  return (unsigned short)(u >> 16);
}

__device__ inline void gload_lds16(const void* g, void* l) {
  __builtin_amdgcn_global_load_lds(
      (const __attribute__((address_space(1))) void*)g,
      (__attribute__((address_space(3))) void*)l, 16, 0, 0);
}

// ---------------- weight transpose + bf16 cast: W[K][N] -> Wt[N][K] ----------
__global__ void wtrans(const float* __restrict__ W, unsigned short* __restrict__ Wt,
                       int K, int N) {
  int idx = blockIdx.x * 256 + threadIdx.x;
  if (idx >= K * N) return;
  int k = idx / N, n = idx - k * N;
  Wt[(size_t)n * K + k] = f2bf(W[idx]);
}

// ---------------- LayerNorm (+ optional shift/window gather), f32 -> bf16 ----
template <int MODE>
__global__ void ln_k(const float* __restrict__ x, const float* __restrict__ sc,
                     const float* __restrict__ bi, unsigned short* __restrict__ o) {
  int t = blockIdx.x * 4 + (threadIdx.x >> 6);
  int l = threadIdx.x & 63;
  size_t src;
  if (MODE == 0) {
    int b = t / 28800, r = t - b * 28800;
    int win = r / 144, tok = r - win * 144;
    int c1 = win / 100, rem = win - c1 * 100;
    int h1 = rem / 10, w1 = rem - h1 * 10;
    int tc = tok / 72, tr = tok - tc * 72;
    int th = tr / 12, tw = tr - th * 12;
    int cs = c1 * 2 + tc, hs = h1 * 6 + th, wsp = w1 * 12 + tw;
    int co = (cs + 1) & 3;
    int ho = hs + 3; if (ho >= 60) ho -= 60;
    int wo = wsp + 6; if (wo >= 120) wo -= 120;
    src = ((size_t)b * 28800 + (co * 60 + ho) * 120 + wo) * 512;
  } else {
    src = (size_t)t * 512;
  }
  const float4* xr = (const float4*)(x + src);
  float4 v0 = xr[l * 2], v1 = xr[l * 2 + 1];
  float s = v0.x + v0.y + v0.z + v0.w + v1.x + v1.y + v1.z + v1.w;
  float s2 = v0.x * v0.x + v0.y * v0.y + v0.z * v0.z + v0.w * v0.w +
             v1.x * v1.x + v1.y * v1.y + v1.z * v1.z + v1.w * v1.w;
  #pragma unroll
  for (int o2 = 32; o2; o2 >>= 1) {
    s += __shfl_xor(s, o2);
    s2 += __shfl_xor(s2, o2);
  }
  float mean = s * (1.0f / 512.0f);
  float var = s2 * (1.0f / 512.0f) - mean * mean;
  float inv = rsqrtf(var + 1e-6f);
  const float4* scp = (const float4*)sc;
  const float4* bip = (const float4*)bi;
  float4 sa = scp[l * 2], sb = scp[l * 2 + 1];
  float4 ba = bip[l * 2], bb = bip[l * 2 + 1];
  u16x8 ov;
  ov[0] = f2bf((v0.x - mean) * inv * sa.x + ba.x);
  ov[1] = f2bf((v0.y - mean) * inv * sa.y + ba.y);
  ov[2] = f2bf((v0.z - mean) * inv * sa.z + ba.z);
  ov[3] = f2bf((v0.w - mean) * inv * sa.w + ba.w);
  ov[4] = f2bf((v1.x - mean) * inv * sb.x + bb.x);
  ov[5] = f2bf((v1.y - mean) * inv * sb.y + bb.y);
  ov[6] = f2bf((v1.z - mean) * inv * sb.z + bb.z);
  ov[7] = f2bf((v1.w - mean) * inv * sb.w + bb.w);
  *(u16x8*)&o[(size_t)t * 512 + l * 8] = ov;
}

// ---------------- 256x256 bf16 MFMA GEMM, 8-phase static-slot pipeline -------
// A: M x K row-major bf16.  Bt: N x K row-major bf16.
// 4 static LDS slots of K=32 chunks (A 256x32 + B 256x32 each, 128 KiB total).
// Iteration = 4 chunks (K=128), 8 phases; phase p: slot s=p>>1, half h=p&1.
// Fragment reads via inline-asm ds_read_b128 (opaque to waitcnt pass -> no
// auto vmcnt(0) drain); explicit lgkmcnt(0)+sched_barrier before MFMA.
// Counted vmcnt(8) at odd-phase ends (~6-phase prefetch lead); raw s_barrier.
template <int EPI>
__launch_bounds__(512, 2)
__global__ void gemm256(const unsigned short* __restrict__ A,
                        const unsigned short* __restrict__ Bt,
                        const float* __restrict__ bias, void* __restrict__ outp,
                        const float* __restrict__ res, int M, int N, int K) {
  __shared__ __attribute__((aligned(16))) unsigned short lds[4][2][8192];
  const int tid = threadIdx.x;
  const int w = tid >> 6, l = tid & 63;
  const int wm = (tid >> 8) & 1, wn = (tid >> 6) & 3;
  const int lane15 = l & 15, lk = (l >> 4) << 3;
  const int ntile = N >> 8;
  // bijective XCD-aware swizzle (m204)
  const int nwg = gridDim.x;
  const int q = nwg >> 3, r = nwg & 7;
  const int xcd = blockIdx.x & 7, idx8 = blockIdx.x >> 3;
  const int wgid = (xcd < r ? xcd * (q + 1) : r * (q + 1) + (xcd - r) * q) + idx8;
  const int bm = wgid / ntile, bn = wgid - bm * ntile;
  const unsigned short* Ag = A + (size_t)bm * 256 * K;
  const unsigned short* Bg = Bt + (size_t)bn * 256 * K;
  const int lq = l >> 2;
  const int sc0 = (l & 3) << 3;
  const int scs = sc0 ^ (((lq >> 1) & 3) << 3);  // store-side swizzled k-offset
  const int sw = ((lane15 >> 1) & 3) << 3;       // read-side swizzle

  unsigned lds0 = (unsigned)(unsigned long long)
      (__attribute__((address_space(3))) void*)(void*)&lds[0][0][0];
  const unsigned aA = lds0 + (unsigned)((wm * 128 + lane15) * 64 + ((lk ^ sw) << 1));
  const unsigned aB = lds0 + 16384u + (unsigned)((wn * 64 + lane15) * 64 + ((lk ^ sw) << 1));

  f32x4 acc[8][4] = {};
  bf16x8 af[4], bfr[4];

  auto STAGE = [&](int slot, int part, int c) {
    const unsigned short* gb = part ? Bg : Ag;
    unsigned short* lb = &lds[0][0][0] + slot * 16384 + part * 8192;
    const int kc = c << 5;
    #pragma unroll
    for (int i = 0; i < 2; ++i) {
      int j = i * 8 + w;
      int row = j * 16 + lq;
      gload_lds16(gb + (size_t)row * K + kc + scs, lb + j * 512);
    }
  };
  auto LDA4 = [&](unsigned base) {
    DSR(af[0], base, 0);
    DSR(af[1], base, 1024);
    DSR(af[2], base, 2048);
    DSR(af[3], base, 3072);
  };
  auto LDB4 = [&](unsigned base) {
    DSR(bfr[0], base, 0);
    DSR(bfr[1], base, 1024);
    DSR(bfr[2], base, 2048);
    DSR(bfr[3], base, 3072);
  };
  auto MFMA16 = [&](int h) {
    __builtin_amdgcn_s_setprio(1);
    #pragma unroll
    for (int mf = 0; mf < 4; ++mf)
      #pragma unroll
      for (int nf = 0; nf < 4; ++nf)
        acc[h * 4 + mf][nf] = __builtin_amdgcn_mfma_f32_16x16x32_bf16(
            af[mf], bfr[nf], acc[h * 4 + mf][nf], 0, 0, 0);
    __builtin_amdgcn_s_setprio(0);
  };

  const int NI = K >> 7;  // iterations of 4 chunks (K multiple of 128)

  // prologue: stage slots 0,1,2 (chunks 0,1,2)
  STAGE(0, 0, 0); STAGE(0, 1, 0);
  STAGE(1, 0, 1); STAGE(1, 1, 1);
  STAGE(2, 0, 2); STAGE(2, 1, 2);
  VMC(8);
  BAR();

  for (int i = 0; i < NI - 1; ++i) {
    const int c4 = 4 * i;
    // p0: slot0 h0
    LDA4(aA + 0 * 32768 + 0); LDB4(aB + 0 * 32768);
    STAGE(3, 0, c4 + 3);
    BAR(); WAITL(); MFMA16(0); BAR();
    // p1: slot0 h1
    LDA4(aA + 0 * 32768 + 4096);
    STAGE(3, 1, c4 + 3);
    BAR(); WAITL(); MFMA16(1); VMC(8); BAR();
    // p2: slot1 h0
    LDA4(aA + 1 * 32768 + 0); LDB4(aB + 1 * 32768);
    STAGE(0, 0, c4 + 4);
    BAR(); WAITL(); MFMA16(0); BAR();
    // p3: slot1 h1
    LDA4(aA + 1 * 32768 + 4096);
    STAGE(0, 1, c4 + 4);
    BAR(); WAITL(); MFMA16(1); VMC(8); BAR();
    // p4: slot2 h0
    LDA4(aA + 2 * 32768 + 0); LDB4(aB + 2 * 32768);
    STAGE(1, 0, c4 + 5);
    BAR(); WAITL(); MFMA16(0); BAR();
    // p5: slot2 h1
    LDA4(aA + 2 * 32768 + 4096);
    STAGE(1, 1, c4 + 5);
    BAR(); WAITL(); MFMA16(1); VMC(8); BAR();
    // p6: slot3 h0
    LDA4(aA + 3 * 32768 + 0); LDB4(aB + 3 * 32768);
    STAGE(2, 0, c4 + 6);
    BAR(); WAITL(); MFMA16(0); BAR();
    // p7: slot3 h1
    LDA4(aA + 3 * 32768 + 4096);
    STAGE(2, 1, c4 + 6);
    BAR(); WAITL(); MFMA16(1); VMC(8); BAR();
  }
  {
    const int c4 = 4 * (NI - 1);
    // p0
    LDA4(aA + 0 * 32768 + 0); LDB4(aB + 0 * 32768);
    STAGE(3, 0, c4 + 3);
    BAR(); WAITL(); MFMA16(0); BAR();
    // p1
    LDA4(aA + 0 * 32768 + 4096);
    STAGE(3, 1, c4 + 3);
    BAR(); WAITL(); MFMA16(1); VMC(8); BAR();
    // p2
    LDA4(aA + 1 * 32768 + 0); LDB4(aB + 1 * 32768);
    BAR(); WAITL(); MFMA16(0); BAR();
    // p3
    LDA4(aA + 1 * 32768 + 4096);
    BAR(); WAITL(); MFMA16(1); VMC(4); BAR();
    // p4
    LDA4(aA + 2 * 32768 + 0); LDB4(aB + 2 * 32768);
    BAR(); WAITL(); MFMA16(0); BAR();
    // p5
    LDA4(aA + 2 * 32768 + 4096);
    BAR(); WAITL(); MFMA16(1); VMC(0); BAR();
    // p6
    LDA4(aA + 3 * 32768 + 0); LDB4(aB + 3 * 32768);
    BAR(); WAITL(); MFMA16(0); BAR();
    // p7
    LDA4(aA + 3 * 32768 + 4096);
    BAR(); WAITL(); MFMA16(1); BAR();
  }

  // ---------------- epilogue ----------------
  float* outf = (float*)outp;
  unsigned short* outh = (unsigned short*)outp;
  #pragma unroll
  for (int mi = 0; mi < 8; ++mi) {
    #pragma unroll
    for (int j = 0; j < 4; ++j) {
      int grow = bm * 256 + wm * 128 + mi * 16 + ((l >> 4) << 2) + j;
      int win = 0, tok = 0;
      size_t rowbase = 0;
      if constexpr (EPI == 0) {
        win = grow / 144;
        tok = grow - win * 144;
      } else if constexpr (EPI == 1) {
        win = grow / 144;
        tok = grow - win * 144;
        int b = win / 200, wl = win - b * 200;
        int c1 = wl / 100, rem = wl - c1 * 100;
        int h1 = rem / 10, w1 = rem - h1 * 10;
        int tc = tok / 72, tr = tok - tc * 72;
        int th = tr / 12, tw = tr - th * 12;
        int cs = c1 * 2 + tc, hs = h1 * 6 + th, wsp = w1 * 12 + tw;
        int co = (cs + 1) & 3;
        int ho = hs + 3; if (ho >= 60) ho -= 60;
        int wo = wsp + 6; if (wo >= 120) wo -= 120;
        rowbase = ((size_t)b * 28800 + (co * 60 + ho) * 120 + wo) * 512;
      }
      #pragma unroll
      for (int nf = 0; nf < 4; ++nf) {
        int gcol = bn * 256 + wn * 64 + nf * 16 + lane15;
        float val = acc[mi][nf][j] + bias[gcol];
        if constexpr (EPI == 0) {
          int which = gcol >> 9, hd = (gcol >> 6) & 7, dh = gcol & 63;
          outh[(((size_t)(win * 3 + which) * 8 + hd) * 144 + tok) * 64 + dh] = f2bf(val);
        } else if constexpr (EPI == 1) {
          size_t oi = rowbase + gcol;
          outf[oi] = res[oi] + val;
        } else if constexpr (EPI == 2) {
          float u = 0.7978845608f * (val + 0.044715f * val * val * val);
          float g = val / (1.0f + __expf(-2.0f * u));
          outh[(size_t)grow * N + gcol] = f2bf(g);
        } else {
          size_t oi = (size_t)grow * N + gcol;
          outf[oi] += val;
        }
      }
    }
  }
}

// ---------------- attention: one block per (window, head) -------------------
__launch_bounds__(576)
__global__ void attn_k(const unsigned short* __restrict__ qkv,
                       unsigned short* __restrict__ owin) {
  __shared__ __attribute__((aligned(16))) unsigned short Ks[144 * 72];
  __shared__ __attribute__((aligned(16))) unsigned short Vt[64 * 168];
  __shared__ __attribute__((aligned(16))) unsigned short Ps[144 * 168];
  __shared__ unsigned char gid[144];
  int bid = blockIdx.x;
  int win = bid >> 3, head = bid & 7;
  const unsigned short* qb = qkv + ((size_t)(win * 3 + 0) * 8 + head) * (144 * 64);
  const unsigned short* kb = qkv + ((size_t)(win * 3 + 1) * 8 + head) * (144 * 64);
  const unsigned short* vb = qkv + ((size_t)(win * 3 + 2) * 8 + head) * (144 * 64);
  int tid = threadIdx.x;
  {
    int row = tid >> 2, c0 = (tid & 3) << 4;
    u16x8 ka = *(const u16x8*)(kb + row * 64 + c0);
    u16x8 kc = *(const u16x8*)(kb + row * 64 + c0 + 8);
    *(u16x8*)&Ks[row * 72 + c0] = ka;
    *(u16x8*)&Ks[row * 72 + c0 + 8] = kc;
    u16x8 va = *(const u16x8*)(vb + row * 64 + c0);
    u16x8 vc = *(const u16x8*)(vb + row * 64 + c0 + 8);
    #pragma unroll
    for (int j = 0; j < 8; ++j) Vt[(c0 + j) * 168 + row] = va[j];
    #pragma unroll
    for (int j = 0; j < 8; ++j) Vt[(c0 + 8 + j) * 168 + row] = vc[j];
  }
  for (int i = tid; i < 64 * 24; i += 576) {
    int d = i / 24, m = i - d * 24;
    Vt[d * 168 + 144 + m] = 0;
  }
  for (int i = tid; i < 144 * 24; i += 576) {
    int r = i / 24, c = i - r * 24;
    Ps[r * 168 + 144 + c] = 0;
  }
  if (tid < 144) {
    int wl = win % 200;
    int c1 = wl / 100, rem = wl - c1 * 100;
    int h1 = rem / 10, w1 = rem - h1 * 10;
    int tc = tid / 72, tr = tid - tc * 72;
    int th = tr / 12, tw = tr - th * 12;
    int cs = c1 * 2 + tc, hs = h1 * 6 + th, wsp = w1 * 12 + tw;
    int rc = cs < 2 ? 0 : (cs < 3 ? 1 : 2);
    int rh = hs < 54 ? 0 : (hs < 57 ? 1 : 2);
    int rw = wsp < 108 ? 0 : (wsp < 114 ? 1 : 2);
    if (rw == 1) rw = 2;
    gid[tid] = (unsigned char)(rc * 9 + rh * 3 + rw);
  }
  __syncthreads();
  int wv = tid >> 6, l = tid & 63;
  int lane15 = l & 15, lk = (l >> 4) << 3;
  bf16x8 aq0 = *(const bf16x8*)(qb + (wv * 16 + lane15) * 64 + lk);
  bf16x8 aq1 = *(const bf16x8*)(qb + (wv * 16 + lane15) * 64 + 32 + lk);
  f32x4 sf[9];
  #pragma unroll
  for (int ct = 0; ct < 9; ++ct) {
    f32x4 z = {};
    bf16x8 b0 = *(const bf16x8*)&Ks[(ct * 16 + lane15) * 72 + lk];
    bf16x8 b1 = *(const bf16x8*)&Ks[(ct * 16 + lane15) * 72 + 32 + lk];
    z = __builtin_amdgcn_mfma_f32_16x16x32_bf16(aq0, b0, z, 0, 0, 0);
    z = __builtin_amdgcn_mfma_f32_16x16x32_bf16(aq1, b1, z, 0, 0, 0);
    sf[ct] = z;
  }
  int gi[4];
  #pragma unroll
  for (int j = 0; j < 4; ++j) gi[j] = gid[wv * 16 + ((l >> 4) << 2) + j];
  float mx[4] = {-1e30f, -1e30f, -1e30f, -1e30f};
  #pragma unroll
  for (int ct = 0; ct < 9; ++ct) {
    int gj = gid[ct * 16 + lane15];
    #pragma unroll
    for (int j = 0; j < 4; ++j) {
      float s = sf[ct][j] * 0.125f;
      if (gj != gi[j]) s = -1e30f;
      sf[ct][j] = s;
      mx[j] = fmaxf(mx[j], s);
    }
  }
  #pragma unroll
  for (int o2 = 8; o2; o2 >>= 1)
    #pragma unroll
    for (int j = 0; j < 4; ++j) mx[j] = fmaxf(mx[j], __shfl_xor(mx[j], o2));
  float sm[4] = {0.f, 0.f, 0.f, 0.f};
  #pragma unroll
  for (int ct = 0; ct < 9; ++ct)
    #pragma unroll
    for (int j = 0; j < 4; ++j) {
      float e = __expf(sf[ct][j] - mx[j]);
      sf[ct][j] = e;
      sm[j] += e;
    }
  #pragma unroll
  for (int o2 = 8; o2; o2 >>= 1)
    #pragma unroll
    for (int j = 0; j < 4; ++j) sm[j] += __shfl_xor(sm[j], o2);
  float rs[4];
  #pragma unroll
  for (int j = 0; j < 4; ++j) rs[j] = 1.0f / sm[j];
  #pragma unroll
  for (int ct = 0; ct < 9; ++ct)
    #pragma unroll
    for (int j = 0; j < 4; ++j)
      Ps[(wv * 16 + ((l >> 4) << 2) + j) * 168 + ct * 16 + lane15] =
          f2bf(sf[ct][j] * rs[j]);
  __syncthreads();
  f32x4 of[4] = {};
  #pragma unroll
  for (int ks = 0; ks < 5; ++ks) {
    bf16x8 ap = *(const bf16x8*)&Ps[(wv * 16 + lane15) * 168 + ks * 32 + lk];
    #pragma unroll
    for (int nt = 0; nt < 4; ++nt) {
      bf16x8 bv = *(const bf16x8*)&Vt[(nt * 16 + lane15) * 168 + ks * 32 + lk];
      of[nt] = __builtin_amdgcn_mfma_f32_16x16x32_bf16(ap, bv, of[nt], 0, 0, 0);
    }
  }
  unsigned short* ob = owin + (size_t)win * 144 * 512 + head * 64;
  #pragma unroll
  for (int nt = 0; nt < 4; ++nt)
    #pragma unroll
    for (int j = 0; j < 4; ++j) {
      int row = wv * 16 + ((l >> 4) << 2) + j;
      ob[(size_t)row * 512 + nt * 16 + lane15] = f2bf(of[nt][j]);
    }
}

extern "C" void kernel_launch(void* const* d_in, const int* in_sizes, int n_in,
                              void* d_out, int out_size, void* d_ws, size_t ws_size,
                              hipStream_t stream) {
  const float* x = (const float*)d_in[0];
  const float* qkv_w = (const float*)d_in[1];
  const float* qkv_b = (const float*)d_in[2];
  const float* proj_w = (const float*)d_in[3];
  const float* proj_b = (const float*)d_in[4];
  const float* n1s = (const float*)d_in[5];
  const float* n1b = (const float*)d_in[6];
  const float* n2s = (const float*)d_in[7];
  const float* n2b = (const float*)d_in[8];
  const float* w1 = (const float*)d_in[9];
  const float* b1 = (const float*)d_in[10];
  const float* w2 = (const float*)d_in[11];
  const float* b2 = (const float*)d_in[12];
  float* out = (float*)d_out;
  char* ws = (char*)d_ws;

  unsigned short* WqT = (unsigned short*)(ws);               // 1536x512
  unsigned short* WpT = (unsigned short*)(ws + 1572864);     // 512x512
  unsigned short* W1T = (unsigned short*)(ws + 2097152);     // 2048x512
  unsigned short* W2T = (unsigned short*)(ws + 4194304);     // 512x2048
  unsigned short* hwin = (unsigned short*)(ws + 6291456);    // 57600x512 (also ln2out)
  unsigned short* qkvb = (unsigned short*)(ws + 65273856);   // 57600x1536
  unsigned short* owin = (unsigned short*)(ws + 242221056);  // 57600x512
  unsigned short* mid = qkvb;                                // 57600x2048 (aliases qkv+owin)

  wtrans<<<(512 * 1536 + 255) / 256, 256, 0, stream>>>(qkv_w, WqT, 512, 1536);
  wtrans<<<(512 * 512 + 255) / 256, 256, 0, stream>>>(proj_w, WpT, 512, 512);
  wtrans<<<(512 * 2048 + 255) / 256, 256, 0, stream>>>(w1, W1T, 512, 2048);
  wtrans<<<(2048 * 512 + 255) / 256, 256, 0, stream>>>(w2, W2T, 2048, 512);
  ln_k<0><<<14400, 256, 0, stream>>>(x, n1s, n1b, hwin);
  gemm256<0><<<225 * 6, 512, 0, stream>>>(hwin, WqT, qkv_b, qkvb, nullptr, 57600, 1536, 512);
  attn_k<<<3200, 576, 0, stream>>>(qkvb, owin);
  gemm256<1><<<225 * 2, 512, 0, stream>>>(owin, WpT, proj_b, out, x, 57600, 512, 512);
  ln_k<1><<<14400, 256, 0, stream>>>(out, n2s, n2b, hwin);
  gemm256<2><<<225 * 8, 512, 0, stream>>>(hwin, W1T, b1, mid, nullptr, 57600, 2048, 512);
  gemm256<3><<<225 * 2, 512, 0, stream>>>(mid, W2T, b2, out, nullptr, 57600, 512, 2048);
}

// Round 4
// 793.138 us; speedup vs baseline: 1.1992x; 1.1115x over previous
//
#include <hip/hip_runtime.h>

typedef __attribute__((ext_vector_type(8))) short bf16x8;
typedef __attribute__((ext_vector_type(4))) float f32x4;
typedef __attribute__((ext_vector_type(8))) unsigned short u16x8;

#define BAR() __builtin_amdgcn_s_barrier()
#define VMC(n) asm volatile("s_waitcnt vmcnt(" #n ")" ::: "memory")
#define SB0() __builtin_amdgcn_sched_barrier(0)
#define WAITL() do { asm volatile("s_waitcnt lgkmcnt(0)"); SB0(); } while (0)
#define DSRI(dst, base, imm) \
  asm volatile("ds_read_b128 %0, %1 offset:%2" : "=&v"(dst) : "v"(base), "i"(imm))

__device__ inline unsigned short f2bf(float f) {
  unsigned int u = __float_as_uint(f);
  u += 0x7fffu + ((u >> 16) & 1u);
  return (unsigned short)(u >> 16);
}

__device__ inline void gload_lds16(const void* g, void* l) {
  __builtin_amdgcn_global_load_lds(
      (const __attribute__((address_space(1))) void*)g,
      (__attribute__((address_space(3))) void*)l, 16, 0, 0);
}

// ---------------- weight transpose + bf16 cast: W[K][N] -> Wt[N][K] ----------
__global__ void wtrans(const float* __restrict__ W, unsigned short* __restrict__ Wt,
                       int K, int N) {
  int idx = blockIdx.x * 256 + threadIdx.x;
  if (idx >= K * N) return;
  int k = idx / N, n = idx - k * N;
  Wt[(size_t)n * K + k] = f2bf(W[idx]);
}

// ---------------- LayerNorm (+ optional shift/window gather), f32 -> bf16 ----
template <int MODE>
__global__ void ln_k(const float* __restrict__ x, const float* __restrict__ sc,
                     const float* __restrict__ bi, unsigned short* __restrict__ o) {
  int t = blockIdx.x * 4 + (threadIdx.x >> 6);
  int l = threadIdx.x & 63;
  size_t src;
  if (MODE == 0) {
    int b = t / 28800, r = t - b * 28800;
    int win = r / 144, tok = r - win * 144;
    int c1 = win / 100, rem = win - c1 * 100;
    int h1 = rem / 10, w1 = rem - h1 * 10;
    int tc = tok / 72, tr = tok - tc * 72;
    int th = tr / 12, tw = tr - th * 12;
    int cs = c1 * 2 + tc, hs = h1 * 6 + th, wsp = w1 * 12 + tw;
    int co = (cs + 1) & 3;
    int ho = hs + 3; if (ho >= 60) ho -= 60;
    int wo = wsp + 6; if (wo >= 120) wo -= 120;
    src = ((size_t)b * 28800 + (co * 60 + ho) * 120 + wo) * 512;
  } else {
    src = (size_t)t * 512;
  }
  const float4* xr = (const float4*)(x + src);
  float4 v0 = xr[l * 2], v1 = xr[l * 2 + 1];
  float s = v0.x + v0.y + v0.z + v0.w + v1.x + v1.y + v1.z + v1.w;
  float s2 = v0.x * v0.x + v0.y * v0.y + v0.z * v0.z + v0.w * v0.w +
             v1.x * v1.x + v1.y * v1.y + v1.z * v1.z + v1.w * v1.w;
  #pragma unroll
  for (int o2 = 32; o2; o2 >>= 1) {
    s += __shfl_xor(s, o2);
    s2 += __shfl_xor(s2, o2);
  }
  float mean = s * (1.0f / 512.0f);
  float var = s2 * (1.0f / 512.0f) - mean * mean;
  float inv = rsqrtf(var + 1e-6f);
  const float4* scp = (const float4*)sc;
  const float4* bip = (const float4*)bi;
  float4 sa = scp[l * 2], sb = scp[l * 2 + 1];
  float4 ba = bip[l * 2], bb = bip[l * 2 + 1];
  u16x8 ov;
  ov[0] = f2bf((v0.x - mean) * inv * sa.x + ba.x);
  ov[1] = f2bf((v0.y - mean) * inv * sa.y + ba.y);
  ov[2] = f2bf((v0.z - mean) * inv * sa.z + ba.z);
  ov[3] = f2bf((v0.w - mean) * inv * sa.w + ba.w);
  ov[4] = f2bf((v1.x - mean) * inv * sb.x + bb.x);
  ov[5] = f2bf((v1.y - mean) * inv * sb.y + bb.y);
  ov[6] = f2bf((v1.z - mean) * inv * sb.z + bb.z);
  ov[7] = f2bf((v1.w - mean) * inv * sb.w + bb.w);
  *(u16x8*)&o[(size_t)t * 512 + l * 8] = ov;
}

// ---------------- 128x256 bf16 MFMA GEMM, 3-slot ring, 1 barrier/slot --------
// A: M x K row-major bf16.  Bt: N x K row-major bf16.
// 256 threads / 4 waves; per-wave output 128 x 64.  LDS: 3 slots x (A 128x32
// + B 256x32) = 72 KiB -> 2 blocks/CU (cross-block overlap hides drains).
// Slot body: issue 8 ds_read (ring t) + 6 global_load_lds (stage ring t+2);
// lgkm(0); issue afH reads (drain under MFMA h0); MFMA h0; lgkm(0); MFMA h1;
// vmcnt(6) [2-slot lead]; s_barrier.  XOR swizzle both sides.
template <int EPI>
__launch_bounds__(256, 2)
__global__ void gemmT(const unsigned short* __restrict__ A,
                      const unsigned short* __restrict__ Bt,
                      const float* __restrict__ bias, void* __restrict__ outp,
                      const float* __restrict__ res, int M, int N, int K) {
  __shared__ __attribute__((aligned(16))) unsigned short lds3[3][12288];
  const int tid = threadIdx.x;
  const int w = tid >> 6, l = tid & 63;
  const int lane15 = l & 15, lk = (l >> 4) << 3;
  const int ntile = N >> 8;
  // bijective XCD-aware swizzle (m204)
  const int nwg = gridDim.x;
  const int q = nwg >> 3, r = nwg & 7;
  const int xcd = blockIdx.x & 7, idx8 = blockIdx.x >> 3;
  const int wgid = (xcd < r ? xcd * (q + 1) : r * (q + 1) + (xcd - r) * q) + idx8;
  const int bm = wgid / ntile, bn = wgid - bm * ntile;
  const int KT = K >> 5;  // number of K=32 chunks

  // ---- per-lane staging offsets (bytes into the current K-chunk panel) ----
  const int swzb = ((l >> 3) & 3) << 3;            // store-side swizzle bits
  const int colx = (((l & 3) << 3) ^ swzb);        // swizzled col (elements)
  const int rA0 = (0 * 4 + w) * 16 + (l >> 2);
  const int rA1 = (1 * 4 + w) * 16 + (l >> 2);
  const int offA0 = (rA0 * K + colx) * 2, offA1 = (rA1 * K + colx) * 2;
  int offB[4];
  #pragma unroll
  for (int j = 0; j < 4; ++j)
    offB[j] = (((j * 4 + w) * 16 + (l >> 2)) * K + colx) * 2;

  // ---- LDS read base addresses (per-lane, swizzled) ----
  const int sw = ((lane15 >> 1) & 3) << 3;         // read-side swizzle
  unsigned lds0 = (unsigned)(unsigned long long)
      (__attribute__((address_space(3))) void*)(void*)&lds3[0][0];
  const unsigned comA = (unsigned)(lane15 * 64 + ((lk ^ sw) << 1));
  unsigned bA0 = lds0 + comA;
  unsigned bA1 = bA0 + 24576u, bA2 = bA0 + 49152u;
  const unsigned bOffB = 8192u + ((unsigned)w << 12);
  unsigned bB0 = bA0 + bOffB, bB1 = bA1 + bOffB, bB2 = bA2 + bOffB;

  unsigned short* p0 = &lds3[0][0];
  unsigned short* p1 = &lds3[1][0];
  unsigned short* p2 = &lds3[2][0];

  const char* gA = (const char*)(A + (size_t)bm * 128 * K);
  const char* gB = (const char*)(Bt + (size_t)bn * 256 * K);

  f32x4 acc[8][4] = {};
  bf16x8 afL[4], afH[4], bfr[4];

  auto STAGE = [&](unsigned short* pS, const char* ga, const char* gb) {
    gload_lds16(ga + offA0, pS + w * 512);
    gload_lds16(ga + offA1, pS + 2048 + w * 512);
    #pragma unroll
    for (int j = 0; j < 4; ++j)
      gload_lds16(gb + offB[j], pS + 4096 + (j * 4 + w) * 512);
  };

  // prologue: stage slots 0 and 1
  STAGE(p0, gA, gB); gA += 64; gB += 64;
  STAGE(p1, gA, gB); gA += 64; gB += 64;
  VMC(6);
  BAR();

  for (int t = 0; t < KT; ++t) {
    // issue reads for ring t (bases bA0/bB0 hold current ring)
    DSRI(afL[0], bA0, 0);    DSRI(afL[1], bA0, 1024);
    DSRI(afL[2], bA0, 2048); DSRI(afL[3], bA0, 3072);
    DSRI(bfr[0], bB0, 0);    DSRI(bfr[1], bB0, 1024);
    DSRI(bfr[2], bB0, 2048); DSRI(bfr[3], bB0, 3072);
    if (t < KT - 2) {        // stage ring (t+2) into storage p2-current
      STAGE(p2, gA, gB);
      gA += 64; gB += 64;
    }
    WAITL();                 // afL + bfr resident
    DSRI(afH[0], bA0, 4096); DSRI(afH[1], bA0, 5120);
    DSRI(afH[2], bA0, 6144); DSRI(afH[3], bA0, 7168);
    SB0();
    __builtin_amdgcn_s_setprio(1);
    #pragma unroll
    for (int mf = 0; mf < 4; ++mf)
      #pragma unroll
      for (int nf = 0; nf < 4; ++nf)
        acc[mf][nf] = __builtin_amdgcn_mfma_f32_16x16x32_bf16(
            afL[mf], bfr[nf], acc[mf][nf], 0, 0, 0);
    __builtin_amdgcn_s_setprio(0);
    WAITL();                 // afH resident (drained under MFMA h0)
    __builtin_amdgcn_s_setprio(1);
    #pragma unroll
    for (int mf = 0; mf < 4; ++mf)
      #pragma unroll
      for (int nf = 0; nf < 4; ++nf)
        acc[4 + mf][nf] = __builtin_amdgcn_mfma_f32_16x16x32_bf16(
            afH[mf], bfr[nf], acc[4 + mf][nf], 0, 0, 0);
    __builtin_amdgcn_s_setprio(0);
    if (t < KT - 2) { VMC(6); } else if (t == KT - 2) { VMC(0); }
    if (t < KT - 1) BAR();
    // rotate ring
    unsigned ta = bA0; bA0 = bA1; bA1 = bA2; bA2 = ta;
    unsigned tb = bB0; bB0 = bB1; bB1 = bB2; bB2 = tb;
    unsigned short* tp = p0; p0 = p1; p1 = p2; p2 = tp;
  }

  // ---------------- epilogue ----------------
  float* outf = (float*)outp;
  unsigned short* outh = (unsigned short*)outp;
  #pragma unroll
  for (int mi = 0; mi < 8; ++mi) {
    #pragma unroll
    for (int j = 0; j < 4; ++j) {
      int grow = bm * 128 + mi * 16 + ((l >> 4) << 2) + j;
      int win = 0, tok = 0;
      size_t rowbase = 0;
      if constexpr (EPI == 0) {
        win = grow / 144;
        tok = grow - win * 144;
      } else if constexpr (EPI == 1) {
        win = grow / 144;
        tok = grow - win * 144;
        int b = win / 200, wl = win - b * 200;
        int c1 = wl / 100, rem = wl - c1 * 100;
        int h1 = rem / 10, w1 = rem - h1 * 10;
        int tc = tok / 72, tr = tok - tc * 72;
        int th = tr / 12, tw = tr - th * 12;
        int cs = c1 * 2 + tc, hs = h1 * 6 + th, wsp = w1 * 12 + tw;
        int co = (cs + 1) & 3;
        int ho = hs + 3; if (ho >= 60) ho -= 60;
        int wo = wsp + 6; if (wo >= 120) wo -= 120;
        rowbase = ((size_t)b * 28800 + (co * 60 + ho) * 120 + wo) * 512;
      }
      #pragma unroll
      for (int nf = 0; nf < 4; ++nf) {
        int gcol = bn * 256 + w * 64 + nf * 16 + lane15;
        float val = acc[mi][nf][j] + bias[gcol];
        if constexpr (EPI == 0) {
          int which = gcol >> 9, hd = (gcol >> 6) & 7, dh = gcol & 63;
          outh[(((size_t)(win * 3 + which) * 8 + hd) * 144 + tok) * 64 + dh] = f2bf(val);
        } else if constexpr (EPI == 1) {
          size_t oi = rowbase + gcol;
          outf[oi] = res[oi] + val;
        } else if constexpr (EPI == 2) {
          float u = 0.7978845608f * (val + 0.044715f * val * val * val);
          float g = val / (1.0f + __expf(-2.0f * u));
          outh[(size_t)grow * N + gcol] = f2bf(g);
        } else {
          size_t oi = (size_t)grow * N + gcol;
          outf[oi] += val;
        }
      }
    }
  }
}

// ---------------- attention: one block per (window, head) -------------------
__launch_bounds__(576)
__global__ void attn_k(const unsigned short* __restrict__ qkv,
                       unsigned short* __restrict__ owin) {
  __shared__ __attribute__((aligned(16))) unsigned short Ks[144 * 72];
  __shared__ __attribute__((aligned(16))) unsigned short Vt[64 * 168];
  __shared__ __attribute__((aligned(16))) unsigned short Ps[144 * 168];
  __shared__ unsigned char gid[144];
  int bid = blockIdx.x;
  int win = bid >> 3, head = bid & 7;
  const unsigned short* qb = qkv + ((size_t)(win * 3 + 0) * 8 + head) * (144 * 64);
  const unsigned short* kb = qkv + ((size_t)(win * 3 + 1) * 8 + head) * (144 * 64);
  const unsigned short* vb = qkv + ((size_t)(win * 3 + 2) * 8 + head) * (144 * 64);
  int tid = threadIdx.x;
  {
    int row = tid >> 2, c0 = (tid & 3) << 4;
    u16x8 ka = *(const u16x8*)(kb + row * 64 + c0);
    u16x8 kc = *(const u16x8*)(kb + row * 64 + c0 + 8);
    *(u16x8*)&Ks[row * 72 + c0] = ka;
    *(u16x8*)&Ks[row * 72 + c0 + 8] = kc;
    u16x8 va = *(const u16x8*)(vb + row * 64 + c0);
    u16x8 vc = *(const u16x8*)(vb + row * 64 + c0 + 8);
    #pragma unroll
    for (int j = 0; j < 8; ++j) Vt[(c0 + j) * 168 + row] = va[j];
    #pragma unroll
    for (int j = 0; j < 8; ++j) Vt[(c0 + 8 + j) * 168 + row] = vc[j];
  }
  for (int i = tid; i < 64 * 24; i += 576) {
    int d = i / 24, m = i - d * 24;
    Vt[d * 168 + 144 + m] = 0;
  }
  for (int i = tid; i < 144 * 24; i += 576) {
    int r = i / 24, c = i - r * 24;
    Ps[r * 168 + 144 + c] = 0;
  }
  if (tid < 144) {
    int wl = win % 200;
    int c1 = wl / 100, rem = wl - c1 * 100;
    int h1 = rem / 10, w1 = rem - h1 * 10;
    int tc = tid / 72, tr = tid - tc * 72;
    int th = tr / 12, tw = tr - th * 12;
    int cs = c1 * 2 + tc, hs = h1 * 6 + th, wsp = w1 * 12 + tw;
    int rc = cs < 2 ? 0 : (cs < 3 ? 1 : 2);
    int rh = hs < 54 ? 0 : (hs < 57 ? 1 : 2);
    int rw = wsp < 108 ? 0 : (wsp < 114 ? 1 : 2);
    if (rw == 1) rw = 2;
    gid[tid] = (unsigned char)(rc * 9 + rh * 3 + rw);
  }
  __syncthreads();
  int wv = tid >> 6, l = tid & 63;
  int lane15 = l & 15, lk = (l >> 4) << 3;
  bf16x8 aq0 = *(const bf16x8*)(qb + (wv * 16 + lane15) * 64 + lk);
  bf16x8 aq1 = *(const bf16x8*)(qb + (wv * 16 + lane15) * 64 + 32 + lk);
  f32x4 sf[9];
  #pragma unroll
  for (int ct = 0; ct < 9; ++ct) {
    f32x4 z = {};
    bf16x8 b0 = *(const bf16x8*)&Ks[(ct * 16 + lane15) * 72 + lk];
    bf16x8 b1 = *(const bf16x8*)&Ks[(ct * 16 + lane15) * 72 + 32 + lk];
    z = __builtin_amdgcn_mfma_f32_16x16x32_bf16(aq0, b0, z, 0, 0, 0);
    z = __builtin_amdgcn_mfma_f32_16x16x32_bf16(aq1, b1, z, 0, 0, 0);
    sf[ct] = z;
  }
  int gi[4];
  #pragma unroll
  for (int j = 0; j < 4; ++j) gi[j] = gid[wv * 16 + ((l >> 4) << 2) + j];
  float mx[4] = {-1e30f, -1e30f, -1e30f, -1e30f};
  #pragma unroll
  for (int ct = 0; ct < 9; ++ct) {
    int gj = gid[ct * 16 + lane15];
    #pragma unroll
    for (int j = 0; j < 4; ++j) {
      float s = sf[ct][j] * 0.125f;
      if (gj != gi[j]) s = -1e30f;
      sf[ct][j] = s;
      mx[j] = fmaxf(mx[j], s);
    }
  }
  #pragma unroll
  for (int o2 = 8; o2; o2 >>= 1)
    #pragma unroll
    for (int j = 0; j < 4; ++j) mx[j] = fmaxf(mx[j], __shfl_xor(mx[j], o2));
  float sm[4] = {0.f, 0.f, 0.f, 0.f};
  #pragma unroll
  for (int ct = 0; ct < 9; ++ct)
    #pragma unroll
    for (int j = 0; j < 4; ++j) {
      float e = __expf(sf[ct][j] - mx[j]);
      sf[ct][j] = e;
      sm[j] += e;
    }
  #pragma unroll
  for (int o2 = 8; o2; o2 >>= 1)
    #pragma unroll
    for (int j = 0; j < 4; ++j) sm[j] += __shfl_xor(sm[j], o2);
  float rs[4];
  #pragma unroll
  for (int j = 0; j < 4; ++j) rs[j] = 1.0f / sm[j];
  #pragma unroll
  for (int ct = 0; ct < 9; ++ct)
    #pragma unroll
    for (int j = 0; j < 4; ++j)
      Ps[(wv * 16 + ((l >> 4) << 2) + j) * 168 + ct * 16 + lane15] =
          f2bf(sf[ct][j] * rs[j]);
  __syncthreads();
  f32x4 of[4] = {};
  #pragma unroll
  for (int ks = 0; ks < 5; ++ks) {
    bf16x8 ap = *(const bf16x8*)&Ps[(wv * 16 + lane15) * 168 + ks * 32 + lk];
    #pragma unroll
    for (int nt = 0; nt < 4; ++nt) {
      bf16x8 bv = *(const bf16x8*)&Vt[(nt * 16 + lane15) * 168 + ks * 32 + lk];
      of[nt] = __builtin_amdgcn_mfma_f32_16x16x32_bf16(ap, bv, of[nt], 0, 0, 0);
    }
  }
  unsigned short* ob = owin + (size_t)win * 144 * 512 + head * 64;
  #pragma unroll
  for (int nt = 0; nt < 4; ++nt)
    #pragma unroll
    for (int j = 0; j < 4; ++j) {
      int row = wv * 16 + ((l >> 4) << 2) + j;
      ob[(size_t)row * 512 + nt * 16 + lane15] = f2bf(of[nt][j]);
    }
}

extern "C" void kernel_launch(void* const* d_in, const int* in_sizes, int n_in,
                              void* d_out, int out_size, void* d_ws, size_t ws_size,
                              hipStream_t stream) {
  const float* x = (const float*)d_in[0];
  const float* qkv_w = (const float*)d_in[1];
  const float* qkv_b = (const float*)d_in[2];
  const float* proj_w = (const float*)d_in[3];
  const float* proj_b = (const float*)d_in[4];
  const float* n1s = (const float*)d_in[5];
  const float* n1b = (const float*)d_in[6];
  const float* n2s = (const float*)d_in[7];
  const float* n2b = (const float*)d_in[8];
  const float* w1 = (const float*)d_in[9];
  const float* b1 = (const float*)d_in[10];
  const float* w2 = (const float*)d_in[11];
  const float* b2 = (const float*)d_in[12];
  float* out = (float*)d_out;
  char* ws = (char*)d_ws;

  unsigned short* WqT = (unsigned short*)(ws);               // 1536x512
  unsigned short* WpT = (unsigned short*)(ws + 1572864);     // 512x512
  unsigned short* W1T = (unsigned short*)(ws + 2097152);     // 2048x512
  unsigned short* W2T = (unsigned short*)(ws + 4194304);     // 512x2048
  unsigned short* hwin = (unsigned short*)(ws + 6291456);    // 57600x512 (also ln2out)
  unsigned short* qkvb = (unsigned short*)(ws + 65273856);   // 57600x1536
  unsigned short* owin = (unsigned short*)(ws + 242221056);  // 57600x512
  unsigned short* mid = qkvb;                                // 57600x2048 (aliases qkv+owin)

  wtrans<<<(512 * 1536 + 255) / 256, 256, 0, stream>>>(qkv_w, WqT, 512, 1536);
  wtrans<<<(512 * 512 + 255) / 256, 256, 0, stream>>>(proj_w, WpT, 512, 512);
  wtrans<<<(512 * 2048 + 255) / 256, 256, 0, stream>>>(w1, W1T, 512, 2048);
  wtrans<<<(2048 * 512 + 255) / 256, 256, 0, stream>>>(w2, W2T, 2048, 512);
  ln_k<0><<<14400, 256, 0, stream>>>(x, n1s, n1b, hwin);
  gemmT<0><<<450 * 6, 256, 0, stream>>>(hwin, WqT, qkv_b, qkvb, nullptr, 57600, 1536, 512);
  attn_k<<<3200, 576, 0, stream>>>(qkvb, owin);
  gemmT<1><<<450 * 2, 256, 0, stream>>>(owin, WpT, proj_b, out, x, 57600, 512, 512);
  ln_k<1><<<14400, 256, 0, stream>>>(out, n2s, n2b, hwin);
  gemmT<2><<<450 * 8, 256, 0, stream>>>(hwin, W1T, b1, mid, nullptr, 57600, 2048, 512);
  gemmT<3><<<450 * 2, 256, 0, stream>>>(mid, W2T, b2, out, nullptr, 57600, 512, 2048);
}